// Round 1
// baseline (99.231 us; speedup 1.0000x reference)
//
#include <hip/hip_runtime.h>
#include <math.h>

// MaxPool2d: N=32, C=64, H=W=224, kernel=3, stride=2, padding=1 (-inf pad)
// Output: 32 x 64 x 112 x 112 (f32)
//
// Each thread computes 4 consecutive output columns (one "group"):
//   group g covers output cols [4g, 4g+3], needing input cols [8g-1, 8g+7]
//   per input row: two aligned float4 loads + one scalar (left neighbor).
// Left edge (g==0) substitutes -inf for the col -1 element; top row (oh==0)
// skips input row -1 entirely. Right/bottom never touch padding
// (2*111+1 = 223 = last valid index).

#define IH 224
#define IW 224
#define OH 112
#define OW 112
#define OW_GROUPS 28   // 112 / 4

__global__ void maxpool2d_k3s2p1_kernel(const float* __restrict__ in,
                                        float* __restrict__ out,
                                        int total_groups) {
    int idx = blockIdx.x * blockDim.x + threadIdx.x;
    if (idx >= total_groups) return;

    int g    = idx % OW_GROUPS;          // horizontal group of 4 outputs
    int rest = idx / OW_GROUPS;
    int oh   = rest % OH;
    int nc   = rest / OH;                // fused N*C plane index

    const float* base = in + (size_t)nc * (IH * IW);
    const int iw0 = g * 8;               // first input col of the aligned span
    const int ih_start = 2 * oh - 1;

    float m0 = -INFINITY, m1 = -INFINITY, m2 = -INFINITY, m3 = -INFINITY;

    #pragma unroll
    for (int r = 0; r < 3; ++r) {
        int ih = ih_start + r;
        if (ih < 0) continue;            // top padding row (-inf) contributes nothing
        const float* rp = base + (size_t)ih * IW + iw0;
        float4 a = *reinterpret_cast<const float4*>(rp);
        float4 b = *reinterpret_cast<const float4*>(rp + 4);
        float left = (g == 0) ? -INFINITY : rp[-1];

        // windows (relative to iw0): [-1,0,1], [1,2,3], [3,4,5], [5,6,7]
        m0 = fmaxf(m0, fmaxf(left, fmaxf(a.x, a.y)));
        m1 = fmaxf(m1, fmaxf(a.y,  fmaxf(a.z, a.w)));
        m2 = fmaxf(m2, fmaxf(a.w,  fmaxf(b.x, b.y)));
        m3 = fmaxf(m3, fmaxf(b.y,  fmaxf(b.z, b.w)));
    }

    float4 o = make_float4(m0, m1, m2, m3);
    float* op = out + ((size_t)(nc * OH + oh) * OW) + g * 4;
    *reinterpret_cast<float4*>(op) = o;
}

extern "C" void kernel_launch(void* const* d_in, const int* in_sizes, int n_in,
                              void* d_out, int out_size, void* d_ws, size_t ws_size,
                              hipStream_t stream) {
    (void)in_sizes; (void)n_in; (void)d_ws; (void)ws_size; (void)out_size;
    const float* x = (const float*)d_in[0];
    float* out = (float*)d_out;

    const int NC = 32 * 64;
    const int total_groups = NC * OH * OW_GROUPS;   // 6,422,528
    const int block = 256;
    const int grid = (total_groups + block - 1) / block;

    maxpool2d_k3s2p1_kernel<<<grid, block, 0, stream>>>(x, out, total_groups);
}

// Round 3
// 88.736 us; speedup vs baseline: 1.1183x; 1.1183x over previous
//
#include <hip/hip_runtime.h>
#include <math.h>

// MaxPool2d: N=32, C=64, H=W=224, kernel=3, stride=2, padding=1 (-inf pad)
// Output: 32 x 64 x 112 x 112 (f32)
//
// Each thread computes a 4-row x 4-col output tile.
//   cols: group g covers output cols [4g, 4g+3]  -> input cols [8g-1, 8g+7]
//         (two aligned 16B loads + one scalar left element per row)
//   rows: tile t covers output rows [4t, 4t+3]   -> input rows [8t-1, 8t+7]
//         (9 rows per 8 unique -> 1.125x read redundancy instead of 1.5x;
//          overlap rows folded into both output-row accumulators in regs)
// Left edge (g==0) substitutes -inf for col -1; top tile (t==0) skips row -1.
// Right/bottom never touch padding (2*111+1 = 223 = last valid index).

#define IH 224
#define IW 224
#define OH 112
#define OW 112
#define OW_GROUPS 28   // 112 / 4 output cols per thread
#define OH_TILES  28   // 112 / 4 output rows per thread

typedef float f32x4 __attribute__((ext_vector_type(4)));

__global__ void maxpool2d_k3s2p1_kernel(const float* __restrict__ in,
                                        float* __restrict__ out,
                                        int total_tiles) {
    int idx = blockIdx.x * blockDim.x + threadIdx.x;
    if (idx >= total_tiles) return;

    int g    = idx % OW_GROUPS;          // horizontal group of 4 output cols
    int rest = idx / OW_GROUPS;
    int t    = rest % OH_TILES;          // vertical tile of 4 output rows
    int nc   = rest / OH_TILES;          // fused N*C plane index

    const float* base = in + (size_t)nc * (IH * IW);
    const int iw0     = g * 8;           // first input col of the aligned span
    const int ihbase  = t * 8;           // input row for s=0

    float m[4][4];
    #pragma unroll
    for (int lo = 0; lo < 4; ++lo)
        #pragma unroll
        for (int j = 0; j < 4; ++j)
            m[lo][j] = -INFINITY;

    #pragma unroll
    for (int s = -1; s <= 7; ++s) {
        int ih = ihbase + s;
        if (s == -1 && ih < 0) continue;   // top padding row (t==0 only)

        const float* rp = base + (size_t)ih * IW + iw0;
        f32x4 a = *reinterpret_cast<const f32x4*>(rp);
        f32x4 b = *reinterpret_cast<const f32x4*>(rp + 4);
        float left = (g == 0) ? -INFINITY : rp[-1];

        // horizontal window maxes (windows rel. to iw0: [-1,0,1],[1,2,3],[3,4,5],[5,6,7])
        float h0 = fmaxf(left, fmaxf(a.x, a.y));
        float h1 = fmaxf(a.y,  fmaxf(a.z, a.w));
        float h2 = fmaxf(a.w,  fmaxf(b.x, b.y));
        float h3 = fmaxf(b.y,  fmaxf(b.z, b.w));

        // fold into the output rows this input row covers: |s - 2*lo| <= 1
        #pragma unroll
        for (int lo = 0; lo < 4; ++lo) {
            if (s >= 2 * lo - 1 && s <= 2 * lo + 1) {
                m[lo][0] = fmaxf(m[lo][0], h0);
                m[lo][1] = fmaxf(m[lo][1], h1);
                m[lo][2] = fmaxf(m[lo][2], h2);
                m[lo][3] = fmaxf(m[lo][3], h3);
            }
        }
    }

    #pragma unroll
    for (int lo = 0; lo < 4; ++lo) {
        int oh = t * 4 + lo;
        f32x4 o;
        o.x = m[lo][0]; o.y = m[lo][1]; o.z = m[lo][2]; o.w = m[lo][3];
        float* op = out + ((size_t)(nc * OH + oh) * OW) + g * 4;
        __builtin_nontemporal_store(o, reinterpret_cast<f32x4*>(op));
    }
}

extern "C" void kernel_launch(void* const* d_in, const int* in_sizes, int n_in,
                              void* d_out, int out_size, void* d_ws, size_t ws_size,
                              hipStream_t stream) {
    (void)in_sizes; (void)n_in; (void)d_ws; (void)ws_size; (void)out_size;
    const float* x = (const float*)d_in[0];
    float* out = (float*)d_out;

    const int NC = 32 * 64;
    const int total_tiles = NC * OH_TILES * OW_GROUPS;   // 1,605,632
    const int block = 256;
    const int grid = (total_tiles + block - 1) / block;

    maxpool2d_k3s2p1_kernel<<<grid, block, 0, stream>>>(x, out, total_tiles);
}